// Round 1
// baseline (632.988 us; speedup 1.0000x reference)
//
#include <hip/hip_runtime.h>
#include <hip/hip_bf16.h>
#include <math.h>

#define B_ROWS 16384
#define DIM    1024
#define CLS    1000
#define KC     15

typedef __attribute__((ext_vector_type(8))) short short8;
typedef __attribute__((ext_vector_type(4))) float f32x4;

__device__ __forceinline__ unsigned short bf16rtn(float x) {
    unsigned u = __float_as_uint(x);
    unsigned r = (u + 0x7FFFu + ((u >> 16) & 1u)) >> 16;
    return (unsigned short)r;
}

// ---------------- K1: centroid normalize -> bf16, [3][16][1024], row 15 zeroed ----------------
__global__ __launch_bounds__(256) void k1_centnorm(const float* c0, const float* c1, const float* c2,
                                                   unsigned short* cnorm) {
    int bx = blockIdx.x;            // 0..47
    int m = bx >> 4, k = bx & 15;
    int t = threadIdx.x;
    unsigned short* outp = cnorm + ((m * 16 + k) << 10);
    if (k == 15) {
        // zero pad row
        outp[t * 4 + 0] = 0; outp[t * 4 + 1] = 0; outp[t * 4 + 2] = 0; outp[t * 4 + 3] = 0;
        return;
    }
    const float* src = (m == 0 ? c0 : (m == 1 ? c1 : c2)) + (k << 10);
    float4 f = ((const float4*)src)[t];   // 256 threads * 4 floats = 1024
    float s = f.x * f.x + f.y * f.y + f.z * f.z + f.w * f.w;
    for (int d = 1; d < 64; d <<= 1) s += __shfl_xor(s, d);
    __shared__ float r4[4];
    int w = t >> 6, lane = t & 63;
    if (lane == 0) r4[w] = s;
    __syncthreads();
    float tot = r4[0] + r4[1] + r4[2] + r4[3];
    float inv = 1.0f / fmaxf(sqrtf(tot), 1e-12f);
    outp[t * 4 + 0] = bf16rtn(f.x * inv);
    outp[t * 4 + 1] = bf16rtn(f.y * inv);
    outp[t * 4 + 2] = bf16rtn(f.z * inv);
    outp[t * 4 + 3] = bf16rtn(f.w * inv);
}

// ---------------- K2: sims via MFMA; one 16-row tile per wave ----------------
// avg_sim[m][row], assign[m][row]
__global__ __launch_bounds__(256) void k2_sim(const float* f0, const float* f1, const float* f2,
                                              const unsigned short* cnorm, float* avg, int* assign) {
    int t = threadIdx.x;
    int lane = t & 63, w = t >> 6;
    int wg = blockIdx.x * 4 + w;        // 0..3071
    int m = wg >> 10;                   // modality
    int tile = wg & 1023;
    int row_base = tile << 4;
    const float* fea = (m == 0 ? f0 : (m == 1 ? f1 : f2));

    int nrow = lane & 15;               // A row within tile, and B column (cluster)
    int k8 = (lane >> 4) << 3;          // k-slice start within 32-chunk
    const float* aptr = fea + (size_t)(row_base + nrow) * DIM + k8;
    const short8* bptr = (const short8*)(cnorm + ((m * 16 + nrow) << 10) + k8);

    f32x4 acc = {0.0f, 0.0f, 0.0f, 0.0f};
    float nacc = 0.0f;

#pragma unroll 8
    for (int s = 0; s < 32; ++s) {
        float4 a0 = *(const float4*)(aptr + s * 32);
        float4 a1 = *(const float4*)(aptr + s * 32 + 4);
        short8 bfr = bptr[s * 4];       // 32 shorts per k-chunk = 4 short8
        short8 afr;
        afr[0] = (short)bf16rtn(a0.x); afr[1] = (short)bf16rtn(a0.y);
        afr[2] = (short)bf16rtn(a0.z); afr[3] = (short)bf16rtn(a0.w);
        afr[4] = (short)bf16rtn(a1.x); afr[5] = (short)bf16rtn(a1.y);
        afr[6] = (short)bf16rtn(a1.z); afr[7] = (short)bf16rtn(a1.w);
        nacc = fmaf(a0.x, a0.x, nacc);
        nacc = fmaf(a0.y, a0.y, nacc);
        nacc = fmaf(a0.z, a0.z, nacc);
        nacc = fmaf(a0.w, a0.w, nacc);
        nacc = fmaf(a1.x, a1.x, nacc);
        nacc = fmaf(a1.y, a1.y, nacc);
        nacc = fmaf(a1.z, a1.z, nacc);
        nacc = fmaf(a1.w, a1.w, nacc);
        acc = __builtin_amdgcn_mfma_f32_16x16x32_bf16(afr, bfr, acc, 0, 0, 0);
    }

    // full ||row||^2: sum across the 4 quads (lanes l, l^16, l^32, l^48)
    float nsq = nacc;
    nsq += __shfl_xor(nsq, 16);
    nsq += __shfl_xor(nsq, 32);
    float inv = 1.0f / fmaxf(sqrtf(nsq), 1e-12f);   // lane l holds inv-norm of row (l&15)

    int c = lane & 15;                  // C/D col = cluster
    int quad = lane >> 4;
#pragma unroll
    for (int j = 0; j < 4; ++j) {
        int r = quad * 4 + j;           // C/D row
        float invr = __shfl(inv, r);    // lane r (<16) holds row r's inv-norm
        float simv = acc[j] * invr;
        float sv = (c < 15) ? simv : 0.0f;
        float mv = (c < 15) ? simv : -INFINITY;
        int mi = c;
        for (int s = 1; s <= 8; s <<= 1) {
            sv += __shfl_xor(sv, s);
            float ov = __shfl_xor(mv, s);
            int oi = __shfl_xor(mi, s);
            bool take = (ov > mv) || (ov == mv && oi < mi);  // first-index tiebreak
            mv = take ? ov : mv;
            mi = take ? oi : mi;
        }
        if (c == 0) {
            int row = row_base + r;
            avg[m * B_ROWS + row] = sv * (1.0f / 15.0f);
            assign[m * B_ROWS + row] = mi;
        }
    }
}

// ---------------- K3: exact kth-smallest (rank 6554, 0-based) + attractive loss ----------------
__global__ __launch_bounds__(1024) void k3_select(const float* avg, float* attr_out) {
    int m = blockIdx.x;
    int t = threadIdx.x;
    const float* a = avg + m * B_ROWS;
    float av[16];
    unsigned kv[16];
#pragma unroll
    for (int i = 0; i < 16; ++i) {
        float x = a[i * 1024 + t];
        av[i] = x;
        unsigned u = __float_as_uint(x);
        kv[i] = (u & 0x80000000u) ? ~u : (u | 0x80000000u);  // order-preserving key
    }
    __shared__ unsigned sP, sR;
    __shared__ int ri[16];
    __shared__ float rf[16];
    if (t == 0) { sP = 0u; sR = 6554u; }  // kth_idx = 16384 - int(16384*0.6)
    __syncthreads();
    int w = t >> 6, lane = t & 63;
    for (int bit = 31; bit >= 0; --bit) {
        unsigned pref = sP;
        unsigned rr = sR;
        unsigned maskH = (bit == 31) ? 0u : (0xFFFFFFFFu << (bit + 1));
        int cnt = 0;
#pragma unroll
        for (int i = 0; i < 16; ++i) {
            bool match = (((kv[i] ^ pref) & maskH) == 0u);
            bool zero = (((kv[i] >> bit) & 1u) == 0u);
            cnt += (match && zero) ? 1 : 0;
        }
        for (int d = 1; d < 64; d <<= 1) cnt += __shfl_xor(cnt, d);
        if (lane == 0) ri[w] = cnt;
        __syncthreads();
        if (t == 0) {
            int c0 = 0;
            for (int i = 0; i < 16; ++i) c0 += ri[i];
            if ((int)rr >= c0) { sP = pref | (1u << bit); sR = rr - (unsigned)c0; }
        }
        __syncthreads();
    }
    unsigned key = sP;
    float thr = (key & 0x80000000u) ? __uint_as_float(key & 0x7FFFFFFFu)
                                    : __uint_as_float(~key);
    float s = 0.0f;
#pragma unroll
    for (int i = 0; i < 16; ++i) {
        float x = av[i];
        float wgt = 1.0f / (1.0f + __expf(-5.0f * (x - thr)));
        s += wgt * (1.0f - x);
    }
    for (int d = 1; d < 64; d <<= 1) s += __shfl_xor(s, d);
    if (lane == 0) rf[w] = s;
    __syncthreads();
    if (t == 0) {
        float tot = 0.0f;
        for (int i = 0; i < 16; ++i) tot += rf[i];
        attr_out[m] = tot / 16384.0f;
    }
}

// ---------------- K4: per-row sumexp + exact out copy ----------------
__global__ __launch_bounds__(256) void k4_softprep(const float* out_in, float* out_copy, float* inv_denom) {
    int w = threadIdx.x >> 6, lane = threadIdx.x & 63;
    int row = blockIdx.x * 4 + w;
    const float4* src = (const float4*)(out_in + (size_t)row * CLS);
    float4* dst = (float4*)(out_copy + (size_t)row * CLS);
    float s = 0.0f;
#pragma unroll
    for (int i = 0; i < 4; ++i) {
        int idx = i * 64 + lane;
        if (idx < 250) {
            float4 v = src[idx];
            dst[idx] = v;
            s += __expf(v.x) + __expf(v.y) + __expf(v.z) + __expf(v.w);
        }
    }
    for (int d = 1; d < 64; d <<= 1) s += __shfl_xor(s, d);
    if (lane == 0) inv_denom[row] = 1.0f / s;
}

// ---------------- K5: segment accumulation into LDS, deterministic partials ----------------
__global__ __launch_bounds__(1024) void k5_accum(const float* out_in, const float* inv_denom,
                                                 const int* assign, float* partials) {
    __shared__ float acc[3 * KC * 250];   // 45000 B
    int t = threadIdx.x;
    for (int i = t; i < 3 * KC * 250; i += 1024) acc[i] = 0.0f;
    __syncthreads();
    int slot = t >> 8;          // 4 row slots
    int cl = t & 255;           // local column (<250 active)
    int q = blockIdx.y;         // column quarter
    bool active = (cl < 250);
    for (int rb = blockIdx.x * 4; rb < B_ROWS; rb += gridDim.x * 4) {
        int row = rb + slot;
        if (active) {
            float v = out_in[(size_t)row * CLS + q * 250 + cl];
            float p = __expf(v) * inv_denom[row];
            int a0 = assign[row];
            int a1 = assign[B_ROWS + row];
            int a2 = assign[2 * B_ROWS + row];
            atomicAdd(&acc[a0 * 250 + cl], p);
            atomicAdd(&acc[(KC + a1) * 250 + cl], p);
            atomicAdd(&acc[(2 * KC + a2) * 250 + cl], p);
        }
    }
    __syncthreads();
    float* dst = partials + (size_t)(blockIdx.y * gridDim.x + blockIdx.x) * (3 * KC * 250);
    for (int i = t; i < 3 * KC * 250; i += 1024) dst[i] = acc[i];
}

// ---------------- K6: reduce partials -> per-(m,k) entropy, gated on count>=3 ----------------
__global__ __launch_bounds__(256) void k6_entropy(const int* assign, const float* partials,
                                                  int nbq, float* ent_out) {
    int bx = blockIdx.x;        // 0..44
    int m = bx / KC, k = bx % KC;
    int t = threadIdx.x;
    int w = t >> 6, lane = t & 63;
    int cnt = 0;
    for (int e = t; e < B_ROWS; e += 256) cnt += (assign[m * B_ROWS + e] == k) ? 1 : 0;
    for (int d = 1; d < 64; d <<= 1) cnt += __shfl_xor(cnt, d);
    __shared__ int ri[4];
    __shared__ float rf[4];
    if (lane == 0) ri[w] = cnt;
    __syncthreads();
    int count = ri[0] + ri[1] + ri[2] + ri[3];
    float denom = fmaxf((float)count, 1.0f);
    float es = 0.0f;
    for (int c = t; c < CLS; c += 256) {
        int q = c / 250, cl = c % 250;
        float s = 0.0f;
        for (int b = 0; b < nbq; ++b) {
            s += partials[(size_t)(q * nbq + b) * (3 * KC * 250) + (m * KC + k) * 250 + cl];
        }
        float mp = s / denom;
        es += mp * __logf(mp + 1e-8f);
    }
    for (int d = 1; d < 64; d <<= 1) es += __shfl_xor(es, d);
    if (lane == 0) rf[w] = es;
    __syncthreads();
    if (t == 0) {
        float ent = rf[0] + rf[1] + rf[2] + rf[3];
        ent_out[m * KC + k] = (count >= 3) ? ent : 0.0f;
    }
}

// ---------------- K7: final scalar ----------------
__global__ __launch_bounds__(64) void k7_final(const float* attr, const float* ent, float* out_loss) {
    int t = threadIdx.x;
    float v = 0.0f;
    if (t < 45) v = 0.1f * ent[t];
    else if (t < 48) v = 6.0f * attr[t - 45];
    for (int d = 1; d < 64; d <<= 1) v += __shfl_xor(v, d);
    if (t == 0) out_loss[0] = v;
}

extern "C" void kernel_launch(void* const* d_in, const int* in_sizes, int n_in,
                              void* d_out, int out_size, void* d_ws, size_t ws_size,
                              hipStream_t stream) {
    const float* fi = (const float*)d_in[0];
    const float* fo = (const float*)d_in[1];
    const float* ft = (const float*)d_in[2];
    const float* ci = (const float*)d_in[3];
    const float* co = (const float*)d_in[4];
    const float* ct = (const float*)d_in[5];
    const float* outin = (const float*)d_in[6];
    float* dout = (float*)d_out;
    char* ws = (char*)d_ws;

    unsigned short* cnorm = (unsigned short*)(ws + 0);        // 98304 B
    float* avg   = (float*)(ws + 98304);                      // 196608 B
    int* assign  = (int*)(ws + 294912);                       // 196608 B
    float* invd  = (float*)(ws + 491520);                     // 65536 B
    float* attr  = (float*)(ws + 557056);                     // 12 B (pad 256)
    float* ent   = (float*)(ws + 557312);                     // 180 B (pad 256)
    float* partials = (float*)(ws + 557568);

    size_t avail = (ws_size > 557568) ? (ws_size - 557568) : 0;
    int nbq = (int)(avail / (4ull * 45000ull));   // per-quarter K5 blocks; 45000 B partial each, 4 quarters
    if (nbq < 1) nbq = 1;
    if (nbq > 64) nbq = 64;

    hipLaunchKernelGGL(k1_centnorm, dim3(48), dim3(256), 0, stream, ci, co, ct, cnorm);
    hipLaunchKernelGGL(k2_sim, dim3(768), dim3(256), 0, stream, fi, fo, ft, cnorm, avg, assign);
    hipLaunchKernelGGL(k3_select, dim3(3), dim3(1024), 0, stream, avg, attr);
    hipLaunchKernelGGL(k4_softprep, dim3(4096), dim3(256), 0, stream, outin, dout, invd);
    hipLaunchKernelGGL(k5_accum, dim3(nbq, 4), dim3(1024), 0, stream, outin, invd, assign, partials);
    hipLaunchKernelGGL(k6_entropy, dim3(45), dim3(256), 0, stream, assign, partials, nbq, ent);
    hipLaunchKernelGGL(k7_final, dim3(1), dim3(64), 0, stream, attr, ent, dout + 16384000);
}

// Round 2
// 424.878 us; speedup vs baseline: 1.4898x; 1.4898x over previous
//
#include <hip/hip_runtime.h>
#include <hip/hip_bf16.h>
#include <math.h>

#define B_ROWS 16384
#define DIM    1024
#define CLS    1000
#define KC     15

typedef __attribute__((ext_vector_type(8))) short short8;
typedef __attribute__((ext_vector_type(4))) float f32x4;

__device__ __forceinline__ unsigned short bf16rtn(float x) {
    unsigned u = __float_as_uint(x);
    unsigned r = (u + 0x7FFFu + ((u >> 16) & 1u)) >> 16;
    return (unsigned short)r;
}

// ---------------- K1: centroid normalize -> bf16, [3][16][1024], row 15 zeroed ----------------
__global__ __launch_bounds__(256) void k1_centnorm(const float* c0, const float* c1, const float* c2,
                                                   unsigned short* cnorm) {
    int bx = blockIdx.x;            // 0..47
    int m = bx >> 4, k = bx & 15;
    int t = threadIdx.x;
    unsigned short* outp = cnorm + ((m * 16 + k) << 10);
    if (k == 15) {
        outp[t * 4 + 0] = 0; outp[t * 4 + 1] = 0; outp[t * 4 + 2] = 0; outp[t * 4 + 3] = 0;
        return;
    }
    const float* src = (m == 0 ? c0 : (m == 1 ? c1 : c2)) + (k << 10);
    float4 f = ((const float4*)src)[t];
    float s = f.x * f.x + f.y * f.y + f.z * f.z + f.w * f.w;
    for (int d = 1; d < 64; d <<= 1) s += __shfl_xor(s, d);
    __shared__ float r4[4];
    int w = t >> 6, lane = t & 63;
    if (lane == 0) r4[w] = s;
    __syncthreads();
    float tot = r4[0] + r4[1] + r4[2] + r4[3];
    float inv = 1.0f / fmaxf(sqrtf(tot), 1e-12f);
    outp[t * 4 + 0] = bf16rtn(f.x * inv);
    outp[t * 4 + 1] = bf16rtn(f.y * inv);
    outp[t * 4 + 2] = bf16rtn(f.z * inv);
    outp[t * 4 + 3] = bf16rtn(f.w * inv);
}

// ---------------- K2: sims via MFMA; one 16-row tile per wave ----------------
__global__ __launch_bounds__(256) void k2_sim(const float* f0, const float* f1, const float* f2,
                                              const unsigned short* cnorm, float* avg, int* assign) {
    int t = threadIdx.x;
    int lane = t & 63, w = t >> 6;
    int wg = blockIdx.x * 4 + w;        // 0..3071
    int m = wg >> 10;
    int tile = wg & 1023;
    int row_base = tile << 4;
    const float* fea = (m == 0 ? f0 : (m == 1 ? f1 : f2));

    int nrow = lane & 15;
    int k8 = (lane >> 4) << 3;
    const float* aptr = fea + (size_t)(row_base + nrow) * DIM + k8;
    const short8* bptr = (const short8*)(cnorm + ((m * 16 + nrow) << 10) + k8);

    f32x4 acc = {0.0f, 0.0f, 0.0f, 0.0f};
    float nacc = 0.0f;

#pragma unroll 8
    for (int s = 0; s < 32; ++s) {
        float4 a0 = *(const float4*)(aptr + s * 32);
        float4 a1 = *(const float4*)(aptr + s * 32 + 4);
        short8 bfr = bptr[s * 4];
        short8 afr;
        afr[0] = (short)bf16rtn(a0.x); afr[1] = (short)bf16rtn(a0.y);
        afr[2] = (short)bf16rtn(a0.z); afr[3] = (short)bf16rtn(a0.w);
        afr[4] = (short)bf16rtn(a1.x); afr[5] = (short)bf16rtn(a1.y);
        afr[6] = (short)bf16rtn(a1.z); afr[7] = (short)bf16rtn(a1.w);
        nacc = fmaf(a0.x, a0.x, nacc);
        nacc = fmaf(a0.y, a0.y, nacc);
        nacc = fmaf(a0.z, a0.z, nacc);
        nacc = fmaf(a0.w, a0.w, nacc);
        nacc = fmaf(a1.x, a1.x, nacc);
        nacc = fmaf(a1.y, a1.y, nacc);
        nacc = fmaf(a1.z, a1.z, nacc);
        nacc = fmaf(a1.w, a1.w, nacc);
        acc = __builtin_amdgcn_mfma_f32_16x16x32_bf16(afr, bfr, acc, 0, 0, 0);
    }

    float nsq = nacc;
    nsq += __shfl_xor(nsq, 16);
    nsq += __shfl_xor(nsq, 32);
    float inv = 1.0f / fmaxf(sqrtf(nsq), 1e-12f);

    int c = lane & 15;
    int quad = lane >> 4;
#pragma unroll
    for (int j = 0; j < 4; ++j) {
        int r = quad * 4 + j;
        float invr = __shfl(inv, r);
        float simv = acc[j] * invr;
        float sv = (c < 15) ? simv : 0.0f;
        float mv = (c < 15) ? simv : -INFINITY;
        int mi = c;
        for (int s = 1; s <= 8; s <<= 1) {
            sv += __shfl_xor(sv, s);
            float ov = __shfl_xor(mv, s);
            int oi = __shfl_xor(mi, s);
            bool take = (ov > mv) || (ov == mv && oi < mi);
            mv = take ? ov : mv;
            mi = take ? oi : mi;
        }
        if (c == 0) {
            int row = row_base + r;
            avg[m * B_ROWS + row] = sv * (1.0f / 15.0f);
            assign[m * B_ROWS + row] = mi;
        }
    }
}

// ---------------- K3: exact kth-smallest (rank 6554, 0-based) + attractive loss ----------------
__global__ __launch_bounds__(1024) void k3_select(const float* avg, float* attr_out) {
    int m = blockIdx.x;
    int t = threadIdx.x;
    const float* a = avg + m * B_ROWS;
    float av[16];
    unsigned kv[16];
#pragma unroll
    for (int i = 0; i < 16; ++i) {
        float x = a[i * 1024 + t];
        av[i] = x;
        unsigned u = __float_as_uint(x);
        kv[i] = (u & 0x80000000u) ? ~u : (u | 0x80000000u);
    }
    __shared__ unsigned sP, sR;
    __shared__ int ri[16];
    __shared__ float rf[16];
    if (t == 0) { sP = 0u; sR = 6554u; }
    __syncthreads();
    int w = t >> 6, lane = t & 63;
    for (int bit = 31; bit >= 0; --bit) {
        unsigned pref = sP;
        unsigned rr = sR;
        unsigned maskH = (bit == 31) ? 0u : (0xFFFFFFFFu << (bit + 1));
        int cnt = 0;
#pragma unroll
        for (int i = 0; i < 16; ++i) {
            bool match = (((kv[i] ^ pref) & maskH) == 0u);
            bool zero = (((kv[i] >> bit) & 1u) == 0u);
            cnt += (match && zero) ? 1 : 0;
        }
        for (int d = 1; d < 64; d <<= 1) cnt += __shfl_xor(cnt, d);
        if (lane == 0) ri[w] = cnt;
        __syncthreads();
        if (t == 0) {
            int c0 = 0;
            for (int i = 0; i < 16; ++i) c0 += ri[i];
            if ((int)rr >= c0) { sP = pref | (1u << bit); sR = rr - (unsigned)c0; }
        }
        __syncthreads();
    }
    unsigned key = sP;
    float thr = (key & 0x80000000u) ? __uint_as_float(key & 0x7FFFFFFFu)
                                    : __uint_as_float(~key);
    float s = 0.0f;
#pragma unroll
    for (int i = 0; i < 16; ++i) {
        float x = av[i];
        float wgt = 1.0f / (1.0f + __expf(-5.0f * (x - thr)));
        s += wgt * (1.0f - x);
    }
    for (int d = 1; d < 64; d <<= 1) s += __shfl_xor(s, d);
    if (lane == 0) rf[w] = s;
    __syncthreads();
    if (t == 0) {
        float tot = 0.0f;
        for (int i = 0; i < 16; ++i) tot += rf[i];
        attr_out[m] = tot / 16384.0f;
    }
}

// ---------------- K4: per-row sumexp + exact out copy ----------------
__global__ __launch_bounds__(256) void k4_softprep(const float* out_in, float* out_copy, float* inv_denom) {
    int w = threadIdx.x >> 6, lane = threadIdx.x & 63;
    int row = blockIdx.x * 4 + w;
    const float4* src = (const float4*)(out_in + (size_t)row * CLS);
    float4* dst = (float4*)(out_copy + (size_t)row * CLS);
    float s = 0.0f;
#pragma unroll
    for (int i = 0; i < 4; ++i) {
        int idx = i * 64 + lane;
        if (idx < 250) {
            float4 v = src[idx];
            dst[idx] = v;
            s += __expf(v.x) + __expf(v.y) + __expf(v.z) + __expf(v.w);
        }
    }
    for (int d = 1; d < 64; d <<= 1) s += __shfl_xor(s, d);
    if (lane == 0) inv_denom[row] = 1.0f / s;
}

// ---------------- K5: register segment-accumulation, uniform switch (no atomics) ----------------
__device__ __forceinline__ void accsel(float (&a)[KC], int k, float p) {
    switch (k) {
    case 0:  a[0]  += p; break;
    case 1:  a[1]  += p; break;
    case 2:  a[2]  += p; break;
    case 3:  a[3]  += p; break;
    case 4:  a[4]  += p; break;
    case 5:  a[5]  += p; break;
    case 6:  a[6]  += p; break;
    case 7:  a[7]  += p; break;
    case 8:  a[8]  += p; break;
    case 9:  a[9]  += p; break;
    case 10: a[10] += p; break;
    case 11: a[11] += p; break;
    case 12: a[12] += p; break;
    case 13: a[13] += p; break;
    default: a[14] += p; break;
    }
}

__device__ __forceinline__ void phase_out(float (&acc)[KC], float* red, int slot, int cl, int t, float* dst) {
#pragma unroll
    for (int s = 0; s < 4; ++s) {
        if (slot == s) {
#pragma unroll
            for (int k = 0; k < KC; ++k) {
                if (s == 0) red[k * 256 + cl] = acc[k];
                else        red[k * 256 + cl] += acc[k];
            }
        }
        __syncthreads();
    }
    for (int i = t; i < KC * 250; i += 1024) {
        dst[i] = red[(i / 250) * 256 + (i % 250)];
    }
    __syncthreads();
}

__global__ __launch_bounds__(1024) void k5_seg(const float* out_in, const float* inv_denom,
                                               const int* assign, float* partials) {
    int t = threadIdx.x;
    int slot = t >> 8;          // 4 row slots
    int cl = t & 255;           // local column (<250 active)
    int q = blockIdx.y;         // column quarter
    bool active = (cl < 250);
    int colbase = q * 250 + cl;

    float a0acc[KC], a1acc[KC], a2acc[KC];
#pragma unroll
    for (int k = 0; k < KC; ++k) { a0acc[k] = 0.0f; a1acc[k] = 0.0f; a2acc[k] = 0.0f; }

    for (int row = blockIdx.x * 4 + slot; row < B_ROWS; row += 256) {
        float p = 0.0f;
        if (active) p = __expf(out_in[(size_t)row * CLS + colbase]) * inv_denom[row];
        int a0 = assign[row];
        int a1 = assign[B_ROWS + row];
        int a2 = assign[2 * B_ROWS + row];
        accsel(a0acc, a0, p);   // a0 is wave-uniform -> scalar branch, no divergence
        accsel(a1acc, a1, p);
        accsel(a2acc, a2, p);
    }

    __shared__ float red[KC * 256];
    float* dst = partials + (size_t)(blockIdx.y * 64 + blockIdx.x) * (3 * KC * 250);
    phase_out(a0acc, red, slot, cl, t, dst);
    phase_out(a1acc, red, slot, cl, t, dst + KC * 250);
    phase_out(a2acc, red, slot, cl, t, dst + 2 * KC * 250);
}

// ---------------- K6: reduce partials -> per-(m,k) entropy, gated on count>=3 ----------------
__global__ __launch_bounds__(256) void k6_entropy(const int* assign, const float* partials,
                                                  float* ent_out) {
    int bx = blockIdx.x;        // 0..44
    int m = bx / KC, k = bx % KC;
    int t = threadIdx.x;
    int w = t >> 6, lane = t & 63;
    int cnt = 0;
    for (int e = t; e < B_ROWS; e += 256) cnt += (assign[m * B_ROWS + e] == k) ? 1 : 0;
    for (int d = 1; d < 64; d <<= 1) cnt += __shfl_xor(cnt, d);
    __shared__ int ri[4];
    __shared__ float rf[4];
    if (lane == 0) ri[w] = cnt;
    __syncthreads();
    int count = ri[0] + ri[1] + ri[2] + ri[3];
    float denom = fmaxf((float)count, 1.0f);
    float es = 0.0f;
    for (int c = t; c < CLS; c += 256) {
        int cg = c / 250, cl = c % 250;
        float s = 0.0f;
        for (int b = 0; b < 64; ++b) {
            s += partials[(size_t)(cg * 64 + b) * (3 * KC * 250) + (m * KC + k) * 250 + cl];
        }
        float mp = s / denom;
        es += mp * __logf(mp + 1e-8f);
    }
    for (int d = 1; d < 64; d <<= 1) es += __shfl_xor(es, d);
    if (lane == 0) rf[w] = es;
    __syncthreads();
    if (t == 0) {
        float ent = rf[0] + rf[1] + rf[2] + rf[3];
        ent_out[m * KC + k] = (count >= 3) ? ent : 0.0f;
    }
}

// ---------------- K7: final scalar ----------------
__global__ __launch_bounds__(64) void k7_final(const float* attr, const float* ent, float* out_loss) {
    int t = threadIdx.x;
    float v = 0.0f;
    if (t < 45) v = 0.1f * ent[t];
    else if (t < 48) v = 6.0f * attr[t - 45];
    for (int d = 1; d < 64; d <<= 1) v += __shfl_xor(v, d);
    if (t == 0) out_loss[0] = v;
}

extern "C" void kernel_launch(void* const* d_in, const int* in_sizes, int n_in,
                              void* d_out, int out_size, void* d_ws, size_t ws_size,
                              hipStream_t stream) {
    const float* fi = (const float*)d_in[0];
    const float* fo = (const float*)d_in[1];
    const float* ft = (const float*)d_in[2];
    const float* ci = (const float*)d_in[3];
    const float* co = (const float*)d_in[4];
    const float* ct = (const float*)d_in[5];
    const float* outin = (const float*)d_in[6];
    float* dout = (float*)d_out;
    char* ws = (char*)d_ws;

    unsigned short* cnorm = (unsigned short*)(ws + 0);        // 98304 B
    float* avg   = (float*)(ws + 98304);                      // 196608 B
    int* assign  = (int*)(ws + 294912);                       // 196608 B
    float* invd  = (float*)(ws + 491520);                     // 65536 B
    float* attr  = (float*)(ws + 557056);                     // pad 256
    float* ent   = (float*)(ws + 557312);                     // pad 256
    float* partials = (float*)(ws + 557568);                  // 256 * 45000 B = 11.52 MB

    hipLaunchKernelGGL(k1_centnorm, dim3(48), dim3(256), 0, stream, ci, co, ct, cnorm);
    hipLaunchKernelGGL(k2_sim, dim3(768), dim3(256), 0, stream, fi, fo, ft, cnorm, avg, assign);
    hipLaunchKernelGGL(k3_select, dim3(3), dim3(1024), 0, stream, avg, attr);
    hipLaunchKernelGGL(k4_softprep, dim3(4096), dim3(256), 0, stream, outin, dout, invd);
    hipLaunchKernelGGL(k5_seg, dim3(64, 4), dim3(1024), 0, stream, outin, invd, assign, partials);
    hipLaunchKernelGGL(k6_entropy, dim3(45), dim3(256), 0, stream, assign, partials, ent);
    hipLaunchKernelGGL(k7_final, dim3(1), dim3(64), 0, stream, attr, ent, dout + 16384000);
}